// Round 1
// baseline (312.456 us; speedup 1.0000x reference)
//
#include <hip/hip_runtime.h>

// Problem: B=4, N=2048, C=256, ic=128.
// Algebraic restructuring (associativity):
//   Theta = lin(aim, theta), Phi = lin(detect, phi), Gd = lin(detect, g), Ga = lin(aim, g2)
//   X_v := reshape(X_batch, [128, 4096])  (pure view: row i = rows 16i..16i+15 of [2048,256])
//   S_aT = Gd_v @ Phi_v^T          [128,128] per batch
//   S_bT = Ga_v @ Theta_v^T        [128,128] per batch
//   NA_v = S_aT @ Theta_v / 4096   -> flat == [2048,256] tensor
//   ND_v = S_bT @ Phi_v  / 4096
//   out_aim = lin(NA, W) + aim ; out_det = lin(ND, Q) + detect
// Output order: (non_det, non_aim).

#define BKK 16

// C[m,n] = scale * sum_k A[m,k]*B[n,k] + bias[n] + Res[m,n]
// A:[M,K] row-major, B:[N,K] row-major, C:[M,N]. grid: (N/64, M/64, batches)
__global__ __launch_bounds__(256)
void gemm_abt_kernel(const float* __restrict__ A, const float* __restrict__ B,
                     const float* __restrict__ bias, const float* __restrict__ Res,
                     float* __restrict__ Cmat,
                     int M, int N, int K,
                     long sA, long sB, long sC, long sRes, float scale)
{
    __shared__ float As[BKK][68];   // [k][m], padded: store bank-conflict-free
    __shared__ float Bs[BKK][68];   // [k][n]
    const int tid = threadIdx.x;
    const int tx = tid & 15, ty = tid >> 4;
    const int m0 = blockIdx.y * 64, n0 = blockIdx.x * 64;
    const int bz = blockIdx.z;
    A += (long)bz * sA; B += (long)bz * sB; Cmat += (long)bz * sC;
    const float* ResB = Res ? Res + (long)bz * sRes : nullptr;

    float acc[4][4] = {};

    for (int k0 = 0; k0 < K; k0 += BKK) {
        #pragma unroll
        for (int l = 0; l < 4; ++l) {
            int idx = tid + l * 256;
            int r = idx >> 4, c = idx & 15;
            As[c][r] = A[(long)(m0 + r) * K + k0 + c];
            Bs[c][r] = B[(long)(n0 + r) * K + k0 + c];
        }
        __syncthreads();
        #pragma unroll
        for (int k = 0; k < BKK; ++k) {
            float a0[4], b0[4];
            #pragma unroll
            for (int i = 0; i < 4; ++i) a0[i] = As[k][ty * 4 + i];
            #pragma unroll
            for (int j = 0; j < 4; ++j) b0[j] = Bs[k][tx * 4 + j];
            #pragma unroll
            for (int i = 0; i < 4; ++i)
                #pragma unroll
                for (int j = 0; j < 4; ++j)
                    acc[i][j] += a0[i] * b0[j];
        }
        __syncthreads();
    }

    #pragma unroll
    for (int i = 0; i < 4; ++i) {
        int m = m0 + ty * 4 + i;
        #pragma unroll
        for (int j = 0; j < 4; ++j) {
            int n = n0 + tx * 4 + j;
            float v = acc[i][j] * scale;
            if (bias) v += bias[n];
            if (ResB) v += ResB[(long)m * N + n];
            Cmat[(long)m * N + n] = v;
        }
    }
}

// Split-K: C[m,n] += sum_{k in chunk} A[m,k]*B[n,k].  M=N=128, lda=ldb=4096, ldc=128.
// grid: (2, 2, batches*nchunk). C must be pre-zeroed.
__global__ __launch_bounds__(256)
void gemm_abt_splitk_kernel(const float* __restrict__ A, const float* __restrict__ B,
                            float* __restrict__ Cmat,
                            int KC, int nchunk, long sA, long sB, long sC, int lda)
{
    __shared__ float As[BKK][68];
    __shared__ float Bs[BKK][68];
    const int tid = threadIdx.x;
    const int tx = tid & 15, ty = tid >> 4;
    const int m0 = blockIdx.y * 64, n0 = blockIdx.x * 64;
    const int batch = blockIdx.z / nchunk;
    const int chunk = blockIdx.z % nchunk;
    A += (long)batch * sA; B += (long)batch * sB; Cmat += (long)batch * sC;
    const int kbeg = chunk * KC;

    float acc[4][4] = {};

    for (int k0 = kbeg; k0 < kbeg + KC; k0 += BKK) {
        #pragma unroll
        for (int l = 0; l < 4; ++l) {
            int idx = tid + l * 256;
            int r = idx >> 4, c = idx & 15;
            As[c][r] = A[(long)(m0 + r) * lda + k0 + c];
            Bs[c][r] = B[(long)(n0 + r) * lda + k0 + c];
        }
        __syncthreads();
        #pragma unroll
        for (int k = 0; k < BKK; ++k) {
            float a0[4], b0[4];
            #pragma unroll
            for (int i = 0; i < 4; ++i) a0[i] = As[k][ty * 4 + i];
            #pragma unroll
            for (int j = 0; j < 4; ++j) b0[j] = Bs[k][tx * 4 + j];
            #pragma unroll
            for (int i = 0; i < 4; ++i)
                #pragma unroll
                for (int j = 0; j < 4; ++j)
                    acc[i][j] += a0[i] * b0[j];
        }
        __syncthreads();
    }

    #pragma unroll
    for (int i = 0; i < 4; ++i) {
        int m = m0 + ty * 4 + i;
        #pragma unroll
        for (int j = 0; j < 4; ++j) {
            int n = n0 + tx * 4 + j;
            atomicAdd(&Cmat[(long)m * 128 + n], acc[i][j]);
        }
    }
}

// C[m,n] = scale * sum_k A[m,k]*B[k,n].  A:[M,K] rm, B:[K,N] rm.
// grid: (N/64, M/64, batches)
__global__ __launch_bounds__(256)
void gemm_ab_kernel(const float* __restrict__ A, const float* __restrict__ B,
                    float* __restrict__ Cmat,
                    int M, int N, int K, long sA, long sB, long sC, float scale)
{
    __shared__ float As[BKK][68];
    __shared__ float Bs[BKK][68];
    const int tid = threadIdx.x;
    const int tx = tid & 15, ty = tid >> 4;
    const int m0 = blockIdx.y * 64, n0 = blockIdx.x * 64;
    const int bz = blockIdx.z;
    A += (long)bz * sA; B += (long)bz * sB; Cmat += (long)bz * sC;

    float acc[4][4] = {};

    for (int k0 = 0; k0 < K; k0 += BKK) {
        #pragma unroll
        for (int l = 0; l < 4; ++l) {
            int idx = tid + l * 256;
            int rA = idx >> 4, cA = idx & 15;
            As[cA][rA] = A[(long)(m0 + rA) * K + k0 + cA];
            int rB = idx >> 6, cB = idx & 63;   // rB: k-offset 0..15, cB: n-offset 0..63
            Bs[rB][cB] = B[(long)(k0 + rB) * N + n0 + cB];
        }
        __syncthreads();
        #pragma unroll
        for (int k = 0; k < BKK; ++k) {
            float a0[4], b0[4];
            #pragma unroll
            for (int i = 0; i < 4; ++i) a0[i] = As[k][ty * 4 + i];
            #pragma unroll
            for (int j = 0; j < 4; ++j) b0[j] = Bs[k][tx * 4 + j];
            #pragma unroll
            for (int i = 0; i < 4; ++i)
                #pragma unroll
                for (int j = 0; j < 4; ++j)
                    acc[i][j] += a0[i] * b0[j];
        }
        __syncthreads();
    }

    #pragma unroll
    for (int i = 0; i < 4; ++i) {
        int m = m0 + ty * 4 + i;
        #pragma unroll
        for (int j = 0; j < 4; ++j) {
            int n = n0 + tx * 4 + j;
            Cmat[(long)m * N + n] = acc[i][j] * scale;
        }
    }
}

extern "C" void kernel_launch(void* const* d_in, const int* in_sizes, int n_in,
                              void* d_out, int out_size, void* d_ws, size_t ws_size,
                              hipStream_t stream)
{
    const float* detect = (const float*)d_in[0];
    const float* aim    = (const float*)d_in[1];
    const float* g_w  = (const float*)d_in[2];  const float* g_b  = (const float*)d_in[3];
    const float* g2_w = (const float*)d_in[4];  const float* g2_b = (const float*)d_in[5];
    const float* th_w = (const float*)d_in[6];  const float* th_b = (const float*)d_in[7];
    const float* ph_w = (const float*)d_in[8];  const float* ph_b = (const float*)d_in[9];
    const float* W_w  = (const float*)d_in[10]; const float* W_b  = (const float*)d_in[11];
    const float* Q_w  = (const float*)d_in[12]; const float* Q_b  = (const float*)d_in[13];

    const long PB  = 2048L * 256;   // per-batch elements (524288)
    const long TOT = 4 * PB;        // 2097152

    float* ws  = (float*)d_ws;
    float* T   = ws;            // Theta  [4][2048][256]
    float* P   = ws + TOT;      // Phi
    float* Gd  = ws + 2 * TOT;  // g(detect)
    float* Ga  = ws + 3 * TOT;  // g2(aim)
    float* NA  = ws + 4 * TOT;  // pre-W aim tensor
    float* ND  = ws + 5 * TOT;  // pre-Q det tensor
    float* SaT = ws + 6 * TOT;          // [4][128][128]
    float* SbT = SaT + 4 * 128 * 128;   // [4][128][128]

    float* out_det = (float*)d_out;
    float* out_aim = out_det + TOT;

    dim3 blk(256);
    dim3 gLin(4, 128, 1);   // N=256 -> 4 tiles, M=8192 -> 128 tiles

    // 1-4: the four input linears (all batches fused: [8192,256] @ [256,256]^T)
    gemm_abt_kernel<<<gLin, blk, 0, stream>>>(aim,    th_w, th_b, nullptr, T,  8192, 256, 256, 0, 0, 0, 0, 1.0f);
    gemm_abt_kernel<<<gLin, blk, 0, stream>>>(detect, ph_w, ph_b, nullptr, P,  8192, 256, 256, 0, 0, 0, 0, 1.0f);
    gemm_abt_kernel<<<gLin, blk, 0, stream>>>(detect, g_w,  g_b,  nullptr, Gd, 8192, 256, 256, 0, 0, 0, 0, 1.0f);
    gemm_abt_kernel<<<gLin, blk, 0, stream>>>(aim,    g2_w, g2_b, nullptr, Ga, 8192, 256, 256, 0, 0, 0, 0, 1.0f);

    // zero the atomic accumulators (ws is poisoned 0xAA before every call)
    hipMemsetAsync(SaT, 0, 2 * 4 * 128 * 128 * sizeof(float), stream);

    // 5-6: S_aT = Gd_v @ P_v^T ; S_bT = Ga_v @ T_v^T   ([128,4096]@[4096,128], split-K)
    const int nchunk = 16, KC = 4096 / nchunk;
    dim3 gS(2, 2, 4 * nchunk);
    gemm_abt_splitk_kernel<<<gS, blk, 0, stream>>>(Gd, P, SaT, KC, nchunk, PB, PB, 128L * 128, 4096);
    gemm_abt_splitk_kernel<<<gS, blk, 0, stream>>>(Ga, T, SbT, KC, nchunk, PB, PB, 128L * 128, 4096);

    // 7-8: NA_v = S_aT @ T_v / 4096 ; ND_v = S_bT @ P_v / 4096   ([128,128]@[128,4096])
    dim3 gV2(64, 2, 4);
    gemm_ab_kernel<<<gV2, blk, 0, stream>>>(SaT, T, NA, 128, 4096, 128, 128L * 128, PB, PB, 1.0f / 4096.0f);
    gemm_ab_kernel<<<gV2, blk, 0, stream>>>(SbT, P, ND, 128, 4096, 128, 128L * 128, PB, PB, 1.0f / 4096.0f);

    // 9-10: final linears with residual, straight into d_out (order: non_det, non_aim)
    gemm_abt_kernel<<<gLin, blk, 0, stream>>>(NA, W_w, W_b, aim,    out_aim, 8192, 256, 256, 0, 0, 0, 0, 1.0f);
    gemm_abt_kernel<<<gLin, blk, 0, stream>>>(ND, Q_w, Q_b, detect, out_det, 8192, 256, 256, 0, 0, 0, 0, 1.0f);
}

// Round 2
// 148.308 us; speedup vs baseline: 2.1068x; 2.1068x over previous
//
#include <hip/hip_runtime.h>

// B=4, N=2048, C=256, ic=128.  Algebra (validated round 1):
//   T=lin(aim,theta) P=lin(detect,phi) Gd=lin(detect,g) Ga=lin(aim,g2)   [bf16]
//   X_v := per-batch view [128,4096] of [2048,256] (pure reshape)
//   S_aT = Gd_v @ P_v^T ; S_bT = Ga_v @ T_v^T        [128,128] fp32
//   NA_v = S_aT @ T_v /4096 ; ND_v = S_bT @ P_v /4096  [bf16]
//   out_aim = lin(NA,W)+aim ; out_det = lin(ND,Q)+detect  (fp32, order: det,aim)

typedef __attribute__((ext_vector_type(4))) float  f32x4;
typedef __attribute__((ext_vector_type(8))) __bf16 bf16x8;
typedef __attribute__((ext_vector_type(8))) unsigned short u16x8;
typedef __attribute__((ext_vector_type(4))) unsigned short u16x4;

__device__ inline unsigned short f2bf(float f) {
    union { float f; unsigned u; } c; c.f = f;
    unsigned r = c.u + 0x7FFF + ((c.u >> 16) & 1);   // RNE
    return (unsigned short)(r >> 16);
}
__device__ inline bf16x8 ldfrag(const unsigned short* p) {
    return __builtin_bit_cast(bf16x8, *(const u16x8*)p);
}

// ---------------- kernel 1: four input linears -------------------------------
// grid (2,128,2): x=set, y=m-tile(64), z=input(0:aim,1:detect). Tile 64x256, BK=32.
__global__ __launch_bounds__(256)
void lin4_kernel(const float* __restrict__ aim, const float* __restrict__ detect,
                 const float* __restrict__ w_th, const float* __restrict__ b_th,
                 const float* __restrict__ w_g2, const float* __restrict__ b_g2,
                 const float* __restrict__ w_ph, const float* __restrict__ b_ph,
                 const float* __restrict__ w_g,  const float* __restrict__ b_g,
                 unsigned short* __restrict__ T,  unsigned short* __restrict__ Ga,
                 unsigned short* __restrict__ P,  unsigned short* __restrict__ Gd)
{
    const int z = blockIdx.z, set = blockIdx.x;
    const float* A  = z ? detect : aim;
    const float* Wm = z ? (set ? w_g : w_ph) : (set ? w_g2 : w_th);
    const float* Bv = z ? (set ? b_g : b_ph) : (set ? b_g2 : b_th);
    unsigned short* O = z ? (set ? Gd : P) : (set ? Ga : T);
    const int m0 = blockIdx.y * 64;

    __shared__ unsigned short As[64][40];    // [m][k] bf16, stride 40 (80B, 16B-mult)
    __shared__ unsigned short Bs[256][40];   // [n][k]

    const int tid = threadIdx.x, lane = tid & 63, w = tid >> 6;
    const int wr = w >> 1, wc = w & 1, q = lane >> 4, ln = lane & 15;

    f32x4 acc[2][8] = {};

    for (int k0 = 0; k0 < 256; k0 += 32) {
        #pragma unroll
        for (int i = 0; i < 2; ++i) {            // A: 64x32 fp32 = 512 float4
            int c = tid + i * 256, row = c >> 3, c4 = c & 7;
            float4 v = *((const float4*)(A + (size_t)(m0 + row) * 256 + k0) + c4);
            u16x4 p; p[0]=f2bf(v.x); p[1]=f2bf(v.y); p[2]=f2bf(v.z); p[3]=f2bf(v.w);
            *(u16x4*)&As[row][c4 * 4] = p;
        }
        #pragma unroll
        for (int i = 0; i < 8; ++i) {            // W: 256x32 fp32 = 2048 float4
            int c = tid + i * 256, row = c >> 3, c4 = c & 7;
            float4 v = *((const float4*)(Wm + (size_t)row * 256 + k0) + c4);
            u16x4 p; p[0]=f2bf(v.x); p[1]=f2bf(v.y); p[2]=f2bf(v.z); p[3]=f2bf(v.w);
            *(u16x4*)&Bs[row][c4 * 4] = p;
        }
        __syncthreads();
        bf16x8 af[2], bb[8];
        #pragma unroll
        for (int i = 0; i < 2; ++i) af[i] = ldfrag(&As[wr * 32 + i * 16 + ln][q * 8]);
        #pragma unroll
        for (int j = 0; j < 8; ++j) bb[j] = ldfrag(&Bs[wc * 128 + j * 16 + ln][q * 8]);
        #pragma unroll
        for (int i = 0; i < 2; ++i)
            #pragma unroll
            for (int j = 0; j < 8; ++j)
                acc[i][j] = __builtin_amdgcn_mfma_f32_16x16x32_bf16(af[i], bb[j], acc[i][j], 0, 0, 0);
        __syncthreads();
    }

    #pragma unroll
    for (int i = 0; i < 2; ++i)
        #pragma unroll
        for (int j = 0; j < 8; ++j) {
            int n = wc * 128 + j * 16 + ln;
            float bias = Bv[n];
            #pragma unroll
            for (int r = 0; r < 4; ++r) {
                int m = m0 + wr * 32 + i * 16 + q * 4 + r;
                O[(size_t)m * 256 + n] = f2bf(acc[i][j][r] + bias);
            }
        }
}

// ---------------- kernel 2: S partials (split-K) -----------------------------
// grid (256): bz = which*128 + batch*32 + chunk (KC=128, BK=64). Tile 128x128.
__global__ __launch_bounds__(256)
void s_part_kernel(const unsigned short* __restrict__ Gd, const unsigned short* __restrict__ P,
                   const unsigned short* __restrict__ Ga, const unsigned short* __restrict__ T,
                   float* __restrict__ Spart)
{
    const int bz = blockIdx.x;
    const int which = bz >> 7, rem = bz & 127, batch = rem >> 5, chunk = rem & 31;
    const unsigned short* A = (which ? Ga : Gd) + (size_t)batch * 524288;
    const unsigned short* B = (which ? T  : P ) + (size_t)batch * 524288;
    float* out = Spart + ((size_t)(which * 4 + batch) * 32 + chunk) * 16384;
    const int kbeg = chunk * 128;

    __shared__ unsigned short As[128][72], Bs[128][72];   // stride 72 (144B, 16B-mult)
    const int tid = threadIdx.x, lane = tid & 63, w = tid >> 6;
    const int wr = w >> 1, wc = w & 1, q = lane >> 4, ln = lane & 15;

    f32x4 acc[4][4] = {};

    for (int kk = 0; kk < 2; ++kk) {
        const int k0 = kbeg + kk * 64;
        #pragma unroll
        for (int i = 0; i < 4; ++i) {            // 128x64 bf16 = 1024 u16x8 each
            int c = tid + i * 256, row = c >> 3, c8 = c & 7;
            *(u16x8*)&As[row][c8 * 8] = *(const u16x8*)(A + (size_t)row * 4096 + k0 + c8 * 8);
            *(u16x8*)&Bs[row][c8 * 8] = *(const u16x8*)(B + (size_t)row * 4096 + k0 + c8 * 8);
        }
        __syncthreads();
        #pragma unroll
        for (int ks = 0; ks < 2; ++ks) {
            bf16x8 af[4], bb[4];
            #pragma unroll
            for (int i = 0; i < 4; ++i) af[i] = ldfrag(&As[wr * 64 + i * 16 + ln][ks * 32 + q * 8]);
            #pragma unroll
            for (int j = 0; j < 4; ++j) bb[j] = ldfrag(&Bs[wc * 64 + j * 16 + ln][ks * 32 + q * 8]);
            #pragma unroll
            for (int i = 0; i < 4; ++i)
                #pragma unroll
                for (int j = 0; j < 4; ++j)
                    acc[i][j] = __builtin_amdgcn_mfma_f32_16x16x32_bf16(af[i], bb[j], acc[i][j], 0, 0, 0);
        }
        __syncthreads();
    }

    #pragma unroll
    for (int i = 0; i < 4; ++i)
        #pragma unroll
        for (int j = 0; j < 4; ++j)
            #pragma unroll
            for (int r = 0; r < 4; ++r) {
                int m = wr * 64 + i * 16 + q * 4 + r, n = wc * 64 + j * 16 + ln;
                out[m * 128 + n] = acc[i][j][r];
            }
}

// ---------------- kernel 3: reduce S partials --------------------------------
// grid (512): 131072 outputs, one per thread. S layout: [which][batch][128][128].
__global__ __launch_bounds__(256)
void sred_kernel(const float* __restrict__ Spart, float* __restrict__ S)
{
    const int idx = blockIdx.x * 256 + threadIdx.x;
    const int c = idx >> 14, e = idx & 16383;
    float s = 0.f;
    #pragma unroll
    for (int k = 0; k < 32; ++k) s += Spart[((size_t)(c * 32 + k) << 14) + e];
    S[idx] = s;
}

// ---------------- kernel 4: NA/ND = S @ X_v /4096 ----------------------------
// grid (64,1,8): x=j-tile(64), z = which*4+batch. Tile M=128 x N=64, K=128 (one stage).
__global__ __launch_bounds__(256)
void nand_kernel(const float* __restrict__ S,             // [2][4][128][128]
                 const unsigned short* __restrict__ T, const unsigned short* __restrict__ P,
                 unsigned short* __restrict__ NA, unsigned short* __restrict__ ND)
{
    const int which = blockIdx.z >> 2, batch = blockIdx.z & 3;
    const float* Sm = S + (size_t)(which * 4 + batch) * 16384;
    const unsigned short* Bsrc = (which ? P : T) + (size_t)batch * 524288;
    unsigned short* O = (which ? ND : NA) + (size_t)batch * 524288;
    const int j0 = blockIdx.x * 64;

    __shared__ unsigned short As[128][136];   // S bf16 [m][k], stride 136 (272B)
    __shared__ unsigned short Bs[64][136];    // X_v^T  [j][k]

    const int tid = threadIdx.x, lane = tid & 63, w = tid >> 6;
    const int wr = w >> 1, wc = w & 1, q = lane >> 4, ln = lane & 15;

    #pragma unroll
    for (int i = 0; i < 16; ++i) {            // S: 128x128 fp32 = 4096 float4
        int c = tid + i * 256, row = c >> 5, c4 = c & 31;
        float4 v = *((const float4*)(Sm + (size_t)row * 128) + c4);
        u16x4 p; p[0]=f2bf(v.x); p[1]=f2bf(v.y); p[2]=f2bf(v.z); p[3]=f2bf(v.w);
        *(u16x4*)&As[row][c4 * 4] = p;
    }
    #pragma unroll
    for (int i = 0; i < 4; ++i) {             // X_v[k][j0..j0+63] -> Bs[j][k] (transpose)
        int c = tid + i * 256, k = c >> 3, jj0 = (c & 7) * 8;
        u16x8 v = *(const u16x8*)(Bsrc + (size_t)k * 4096 + j0 + jj0);
        #pragma unroll
        for (int jj = 0; jj < 8; ++jj) Bs[jj0 + jj][k] = v[jj];
    }
    __syncthreads();

    f32x4 acc[4][2] = {};
    #pragma unroll
    for (int ks = 0; ks < 4; ++ks) {
        bf16x8 af[4], bb[2];
        #pragma unroll
        for (int i = 0; i < 4; ++i) af[i] = ldfrag(&As[wr * 64 + i * 16 + ln][ks * 32 + q * 8]);
        #pragma unroll
        for (int j = 0; j < 2; ++j) bb[j] = ldfrag(&Bs[wc * 32 + j * 16 + ln][ks * 32 + q * 8]);
        #pragma unroll
        for (int i = 0; i < 4; ++i)
            #pragma unroll
            for (int j = 0; j < 2; ++j)
                acc[i][j] = __builtin_amdgcn_mfma_f32_16x16x32_bf16(af[i], bb[j], acc[i][j], 0, 0, 0);
    }

    #pragma unroll
    for (int i = 0; i < 4; ++i)
        #pragma unroll
        for (int j = 0; j < 2; ++j)
            #pragma unroll
            for (int r = 0; r < 4; ++r) {
                int m = wr * 64 + i * 16 + q * 4 + r;
                int jj = j0 + wc * 32 + j * 16 + ln;
                O[(size_t)m * 4096 + jj] = f2bf(acc[i][j][r] * (1.0f / 4096.0f));
            }
}

// ---------------- kernel 5: final linears + bias + residual ------------------
// grid (2,128,2): x=n-tile(128), y=m-tile(64), z = 0:aim / 1:det. Tile 64x128, BK=32.
__global__ __launch_bounds__(256)
void final_kernel(const unsigned short* __restrict__ NA, const unsigned short* __restrict__ ND,
                  const float* __restrict__ W_w, const float* __restrict__ W_b,
                  const float* __restrict__ Q_w, const float* __restrict__ Q_b,
                  const float* __restrict__ aim, const float* __restrict__ detect,
                  float* __restrict__ out_aim, float* __restrict__ out_det)
{
    const int z = blockIdx.z;
    const unsigned short* A = z ? ND : NA;
    const float* Wm = z ? Q_w : W_w;
    const float* Bv = z ? Q_b : W_b;
    const float* R  = z ? detect : aim;
    float* O = z ? out_det : out_aim;
    const int m0 = blockIdx.y * 64, n0 = blockIdx.x * 128;

    __shared__ unsigned short As[64][40], Bs[128][40];
    const int tid = threadIdx.x, lane = tid & 63, w = tid >> 6;
    const int wr = w >> 1, wc = w & 1, q = lane >> 4, ln = lane & 15;

    f32x4 acc[2][4] = {};

    for (int k0 = 0; k0 < 256; k0 += 32) {
        {                                        // A bf16: 64x32 = 256 u16x8
            int row = tid >> 2, c8 = tid & 3;
            *(u16x8*)&As[row][c8 * 8] = *(const u16x8*)(A + (size_t)(m0 + row) * 256 + k0 + c8 * 8);
        }
        #pragma unroll
        for (int i = 0; i < 4; ++i) {            // W fp32: 128x32 = 1024 float4
            int c = tid + i * 256, row = c >> 3, c4 = c & 7;
            float4 v = *((const float4*)(Wm + (size_t)(n0 + row) * 256 + k0) + c4);
            u16x4 p; p[0]=f2bf(v.x); p[1]=f2bf(v.y); p[2]=f2bf(v.z); p[3]=f2bf(v.w);
            *(u16x4*)&Bs[row][c4 * 4] = p;
        }
        __syncthreads();
        bf16x8 af[2], bb[4];
        #pragma unroll
        for (int i = 0; i < 2; ++i) af[i] = ldfrag(&As[wr * 32 + i * 16 + ln][q * 8]);
        #pragma unroll
        for (int j = 0; j < 4; ++j) bb[j] = ldfrag(&Bs[wc * 64 + j * 16 + ln][q * 8]);
        #pragma unroll
        for (int i = 0; i < 2; ++i)
            #pragma unroll
            for (int j = 0; j < 4; ++j)
                acc[i][j] = __builtin_amdgcn_mfma_f32_16x16x32_bf16(af[i], bb[j], acc[i][j], 0, 0, 0);
        __syncthreads();
    }

    #pragma unroll
    for (int i = 0; i < 2; ++i)
        #pragma unroll
        for (int j = 0; j < 4; ++j) {
            int n = n0 + wc * 64 + j * 16 + ln;
            float bias = Bv[n];
            #pragma unroll
            for (int r = 0; r < 4; ++r) {
                int m = m0 + wr * 32 + i * 16 + q * 4 + r;
                O[(size_t)m * 256 + n] = acc[i][j][r] + bias + R[(size_t)m * 256 + n];
            }
        }
}

extern "C" void kernel_launch(void* const* d_in, const int* in_sizes, int n_in,
                              void* d_out, int out_size, void* d_ws, size_t ws_size,
                              hipStream_t stream)
{
    const float* detect = (const float*)d_in[0];
    const float* aim    = (const float*)d_in[1];
    const float* g_w  = (const float*)d_in[2];  const float* g_b  = (const float*)d_in[3];
    const float* g2_w = (const float*)d_in[4];  const float* g2_b = (const float*)d_in[5];
    const float* th_w = (const float*)d_in[6];  const float* th_b = (const float*)d_in[7];
    const float* ph_w = (const float*)d_in[8];  const float* ph_b = (const float*)d_in[9];
    const float* W_w  = (const float*)d_in[10]; const float* W_b  = (const float*)d_in[11];
    const float* Q_w  = (const float*)d_in[12]; const float* Q_b  = (const float*)d_in[13];

    const size_t TOT = 8192L * 256;   // 2,097,152 elems per bf16 tensor

    unsigned short* ws16 = (unsigned short*)d_ws;
    unsigned short* T  = ws16;
    unsigned short* P  = T  + TOT;
    unsigned short* Gd = P  + TOT;
    unsigned short* Ga = Gd + TOT;
    unsigned short* NA = Ga + TOT;
    unsigned short* ND = NA + TOT;
    float* S     = (float*)(ND + TOT);        // [2][4][128][128]
    float* Spart = S + 2 * 4 * 16384;         // [2][4][32][128][128]

    float* out_det = (float*)d_out;
    float* out_aim = out_det + TOT;

    lin4_kernel<<<dim3(2, 128, 2), 256, 0, stream>>>(
        aim, detect, th_w, th_b, g2_w, g2_b, ph_w, ph_b, g_w, g_b, T, Ga, P, Gd);
    s_part_kernel<<<dim3(256), 256, 0, stream>>>(Gd, P, Ga, T, Spart);
    sred_kernel<<<dim3(512), 256, 0, stream>>>(Spart, S);
    nand_kernel<<<dim3(64, 1, 8), 256, 0, stream>>>(S, T, P, NA, ND);
    final_kernel<<<dim3(2, 128, 2), 256, 0, stream>>>(
        NA, ND, W_w, W_b, Q_w, Q_b, aim, detect, out_aim, out_det);
}

// Round 3
// 137.887 us; speedup vs baseline: 2.2660x; 1.0756x over previous
//
#include <hip/hip_runtime.h>

// B=4, N=2048, C=256, ic=128.  Algebra (validated rounds 1-2):
//   T=lin(aim,theta) P=lin(detect,phi) Gd=lin(detect,g) Ga=lin(aim,g2)   [bf16]
//   X_v := per-batch view [128,4096] of [2048,256] (pure reshape)
//   S_aT = Gd_v @ P_v^T ; S_bT = Ga_v @ T_v^T        [128,128] fp32 (split-K + reduce)
//   NA_v = S_aT @ T_v /4096 ; ND_v = S_bT @ P_v /4096  [bf16]
//   out_aim = lin(NA,W)+aim ; out_det = lin(ND,Q)+detect  (fp32, order: det,aim)
// Round 3: pre-convert weights + inputs to bf16 ONCE (prep kernel); lin4/final
// stage pure bf16 (removes ~200 MB redundant fp32 weight traffic + ~130M VALU
// conversion instructions).

typedef __attribute__((ext_vector_type(4))) float  f32x4;
typedef __attribute__((ext_vector_type(8))) __bf16 bf16x8;
typedef __attribute__((ext_vector_type(8))) unsigned short u16x8;
typedef __attribute__((ext_vector_type(4))) unsigned short u16x4;

__device__ inline unsigned short f2bf(float f) {
    union { float f; unsigned u; } c; c.f = f;
    unsigned r = c.u + 0x7FFF + ((c.u >> 16) & 1);   // RNE
    return (unsigned short)(r >> 16);
}
__device__ inline bf16x8 ldfrag(const unsigned short* p) {
    return __builtin_bit_cast(bf16x8, *(const u16x8*)p);
}

// ---------------- kernel 0: fp32 -> bf16 prep --------------------------------
// dst layout: [6][65536] weights (g,g2,th,ph,W,Q), then aim [2M], detect [2M].
// grid (256, 8), block 256.
__global__ __launch_bounds__(256)
void prep_kernel(const float* __restrict__ g_w, const float* __restrict__ g2_w,
                 const float* __restrict__ th_w, const float* __restrict__ ph_w,
                 const float* __restrict__ W_w, const float* __restrict__ Q_w,
                 const float* __restrict__ aim, const float* __restrict__ detect,
                 unsigned short* __restrict__ dst)
{
    const int z = blockIdx.y;
    const float* src; size_t n4; unsigned short* o;
    if (z == 0)      { src = g_w;    n4 = 16384;  o = dst; }
    else if (z == 1) { src = g2_w;   n4 = 16384;  o = dst + 65536; }
    else if (z == 2) { src = th_w;   n4 = 16384;  o = dst + 2 * 65536; }
    else if (z == 3) { src = ph_w;   n4 = 16384;  o = dst + 3 * 65536; }
    else if (z == 4) { src = W_w;    n4 = 16384;  o = dst + 4 * 65536; }
    else if (z == 5) { src = Q_w;    n4 = 16384;  o = dst + 5 * 65536; }
    else if (z == 6) { src = aim;    n4 = 524288; o = dst + 6 * 65536; }
    else             { src = detect; n4 = 524288; o = dst + 6 * 65536 + 2097152; }
    const size_t stride = (size_t)gridDim.x * 256;
    for (size_t i = blockIdx.x * 256 + threadIdx.x; i < n4; i += stride) {
        float4 v = ((const float4*)src)[i];
        u16x4 p; p[0]=f2bf(v.x); p[1]=f2bf(v.y); p[2]=f2bf(v.z); p[3]=f2bf(v.w);
        ((u16x4*)o)[i] = p;
    }
}

// ---------------- kernel 1: four input linears (all-bf16 staging) ------------
// grid (2,128,2): x=set, y=m-tile(64), z=input(0:aim,1:detect). Tile 64x256, BK=32.
__global__ __launch_bounds__(256)
void lin4_kernel(const unsigned short* __restrict__ Abf, const unsigned short* __restrict__ Dbf,
                 const unsigned short* __restrict__ Wb,   // [6][65536]
                 const float* __restrict__ b_g, const float* __restrict__ b_g2,
                 const float* __restrict__ b_th, const float* __restrict__ b_ph,
                 unsigned short* __restrict__ T,  unsigned short* __restrict__ Ga,
                 unsigned short* __restrict__ P,  unsigned short* __restrict__ Gd)
{
    const int z = blockIdx.z, set = blockIdx.x;
    const unsigned short* A = z ? Dbf : Abf;
    const int wslot = z ? (set ? 0 : 3) : (set ? 1 : 2);   // g / ph / g2 / th
    const unsigned short* Wm = Wb + (size_t)wslot * 65536;
    const float* Bv = z ? (set ? b_g : b_ph) : (set ? b_g2 : b_th);
    unsigned short* O = z ? (set ? Gd : P) : (set ? Ga : T);
    const int m0 = blockIdx.y * 64;

    __shared__ unsigned short As[64][40];    // [m][k] bf16, stride 40 (80B, 16B-mult)
    __shared__ unsigned short Bs[256][40];   // [n][k]

    const int tid = threadIdx.x, lane = tid & 63, w = tid >> 6;
    const int wr = w >> 1, wc = w & 1, q = lane >> 4, ln = lane & 15;

    f32x4 acc[2][8] = {};

    for (int k0 = 0; k0 < 256; k0 += 32) {
        {                                        // A: 64x32 bf16 = 256 u16x8
            int row = tid >> 2, c8 = tid & 3;
            *(u16x8*)&As[row][c8 * 8] = *(const u16x8*)(A + (size_t)(m0 + row) * 256 + k0 + c8 * 8);
        }
        #pragma unroll
        for (int i = 0; i < 4; ++i) {            // W: 256x32 bf16 = 1024 u16x8
            int c = tid + i * 256, row = c >> 2, c8 = c & 3;
            *(u16x8*)&Bs[row][c8 * 8] = *(const u16x8*)(Wm + (size_t)row * 256 + k0 + c8 * 8);
        }
        __syncthreads();
        bf16x8 af[2], bb[8];
        #pragma unroll
        for (int i = 0; i < 2; ++i) af[i] = ldfrag(&As[wr * 32 + i * 16 + ln][q * 8]);
        #pragma unroll
        for (int j = 0; j < 8; ++j) bb[j] = ldfrag(&Bs[wc * 128 + j * 16 + ln][q * 8]);
        #pragma unroll
        for (int i = 0; i < 2; ++i)
            #pragma unroll
            for (int j = 0; j < 8; ++j)
                acc[i][j] = __builtin_amdgcn_mfma_f32_16x16x32_bf16(af[i], bb[j], acc[i][j], 0, 0, 0);
        __syncthreads();
    }

    #pragma unroll
    for (int i = 0; i < 2; ++i)
        #pragma unroll
        for (int j = 0; j < 8; ++j) {
            int n = wc * 128 + j * 16 + ln;
            float bias = Bv[n];
            #pragma unroll
            for (int r = 0; r < 4; ++r) {
                int m = m0 + wr * 32 + i * 16 + q * 4 + r;
                O[(size_t)m * 256 + n] = f2bf(acc[i][j][r] + bias);
            }
        }
}

// ---------------- kernel 2: S partials (split-K) -----------------------------
// grid (256): bz = which*128 + batch*32 + chunk (KC=128, BK=64). Tile 128x128.
__global__ __launch_bounds__(256)
void s_part_kernel(const unsigned short* __restrict__ Gd, const unsigned short* __restrict__ P,
                   const unsigned short* __restrict__ Ga, const unsigned short* __restrict__ T,
                   float* __restrict__ Spart)
{
    const int bz = blockIdx.x;
    const int which = bz >> 7, rem = bz & 127, batch = rem >> 5, chunk = rem & 31;
    const unsigned short* A = (which ? Ga : Gd) + (size_t)batch * 524288;
    const unsigned short* B = (which ? T  : P ) + (size_t)batch * 524288;
    float* out = Spart + ((size_t)(which * 4 + batch) * 32 + chunk) * 16384;
    const int kbeg = chunk * 128;

    __shared__ unsigned short As[128][72], Bs[128][72];   // stride 72 (144B, 16B-mult)
    const int tid = threadIdx.x, lane = tid & 63, w = tid >> 6;
    const int wr = w >> 1, wc = w & 1, q = lane >> 4, ln = lane & 15;

    f32x4 acc[4][4] = {};

    for (int kk = 0; kk < 2; ++kk) {
        const int k0 = kbeg + kk * 64;
        #pragma unroll
        for (int i = 0; i < 4; ++i) {            // 128x64 bf16 = 1024 u16x8 each
            int c = tid + i * 256, row = c >> 3, c8 = c & 7;
            *(u16x8*)&As[row][c8 * 8] = *(const u16x8*)(A + (size_t)row * 4096 + k0 + c8 * 8);
            *(u16x8*)&Bs[row][c8 * 8] = *(const u16x8*)(B + (size_t)row * 4096 + k0 + c8 * 8);
        }
        __syncthreads();
        #pragma unroll
        for (int ks = 0; ks < 2; ++ks) {
            bf16x8 af[4], bb[4];
            #pragma unroll
            for (int i = 0; i < 4; ++i) af[i] = ldfrag(&As[wr * 64 + i * 16 + ln][ks * 32 + q * 8]);
            #pragma unroll
            for (int j = 0; j < 4; ++j) bb[j] = ldfrag(&Bs[wc * 64 + j * 16 + ln][ks * 32 + q * 8]);
            #pragma unroll
            for (int i = 0; i < 4; ++i)
                #pragma unroll
                for (int j = 0; j < 4; ++j)
                    acc[i][j] = __builtin_amdgcn_mfma_f32_16x16x32_bf16(af[i], bb[j], acc[i][j], 0, 0, 0);
        }
        __syncthreads();
    }

    #pragma unroll
    for (int i = 0; i < 4; ++i)
        #pragma unroll
        for (int j = 0; j < 4; ++j)
            #pragma unroll
            for (int r = 0; r < 4; ++r) {
                int m = wr * 64 + i * 16 + q * 4 + r, n = wc * 64 + j * 16 + ln;
                out[m * 128 + n] = acc[i][j][r];
            }
}

// ---------------- kernel 3: reduce S partials --------------------------------
// grid (512): 131072 outputs, one per thread. S layout: [which][batch][128][128].
__global__ __launch_bounds__(256)
void sred_kernel(const float* __restrict__ Spart, float* __restrict__ S)
{
    const int idx = blockIdx.x * 256 + threadIdx.x;
    const int c = idx >> 14, e = idx & 16383;
    float s = 0.f;
    #pragma unroll
    for (int k = 0; k < 32; ++k) s += Spart[((size_t)(c * 32 + k) << 14) + e];
    S[idx] = s;
}

// ---------------- kernel 4: NA/ND = S @ X_v /4096 ----------------------------
// grid (64,1,8): x=j-tile(64), z = which*4+batch. Tile M=128 x N=64, K=128 (one stage).
__global__ __launch_bounds__(256)
void nand_kernel(const float* __restrict__ S,             // [2][4][128][128]
                 const unsigned short* __restrict__ T, const unsigned short* __restrict__ P,
                 unsigned short* __restrict__ NA, unsigned short* __restrict__ ND)
{
    const int which = blockIdx.z >> 2, batch = blockIdx.z & 3;
    const float* Sm = S + (size_t)(which * 4 + batch) * 16384;
    const unsigned short* Bsrc = (which ? P : T) + (size_t)batch * 524288;
    unsigned short* O = (which ? ND : NA) + (size_t)batch * 524288;
    const int j0 = blockIdx.x * 64;

    __shared__ unsigned short As[128][136];   // S bf16 [m][k], stride 136 (272B)
    __shared__ unsigned short Bs[64][136];    // X_v^T  [j][k]

    const int tid = threadIdx.x, lane = tid & 63, w = tid >> 6;
    const int wr = w >> 1, wc = w & 1, q = lane >> 4, ln = lane & 15;

    #pragma unroll
    for (int i = 0; i < 16; ++i) {            // S: 128x128 fp32 = 4096 float4
        int c = tid + i * 256, row = c >> 5, c4 = c & 31;
        float4 v = *((const float4*)(Sm + (size_t)row * 128) + c4);
        u16x4 p; p[0]=f2bf(v.x); p[1]=f2bf(v.y); p[2]=f2bf(v.z); p[3]=f2bf(v.w);
        *(u16x4*)&As[row][c4 * 4] = p;
    }
    #pragma unroll
    for (int i = 0; i < 4; ++i) {             // X_v[k][j0..j0+63] -> Bs[j][k] (transpose)
        int c = tid + i * 256, k = c >> 3, jj0 = (c & 7) * 8;
        u16x8 v = *(const u16x8*)(Bsrc + (size_t)k * 4096 + j0 + jj0);
        #pragma unroll
        for (int jj = 0; jj < 8; ++jj) Bs[jj0 + jj][k] = v[jj];
    }
    __syncthreads();

    f32x4 acc[4][2] = {};
    #pragma unroll
    for (int ks = 0; ks < 4; ++ks) {
        bf16x8 af[4], bb[2];
        #pragma unroll
        for (int i = 0; i < 4; ++i) af[i] = ldfrag(&As[wr * 64 + i * 16 + ln][ks * 32 + q * 8]);
        #pragma unroll
        for (int j = 0; j < 2; ++j) bb[j] = ldfrag(&Bs[wc * 32 + j * 16 + ln][ks * 32 + q * 8]);
        #pragma unroll
        for (int i = 0; i < 4; ++i)
            #pragma unroll
            for (int j = 0; j < 2; ++j)
                acc[i][j] = __builtin_amdgcn_mfma_f32_16x16x32_bf16(af[i], bb[j], acc[i][j], 0, 0, 0);
    }

    #pragma unroll
    for (int i = 0; i < 4; ++i)
        #pragma unroll
        for (int j = 0; j < 2; ++j)
            #pragma unroll
            for (int r = 0; r < 4; ++r) {
                int m = wr * 64 + i * 16 + q * 4 + r;
                int jj = j0 + wc * 32 + j * 16 + ln;
                O[(size_t)m * 4096 + jj] = f2bf(acc[i][j][r] * (1.0f / 4096.0f));
            }
}

// ---------------- kernel 5: final linears + bias + residual ------------------
// grid (2,128,2): x=n-tile(128), y=m-tile(64), z = 0:aim / 1:det. Tile 64x128, BK=32.
__global__ __launch_bounds__(256)
void final_kernel(const unsigned short* __restrict__ NA, const unsigned short* __restrict__ ND,
                  const unsigned short* __restrict__ Wb,   // [6][65536], slots 4/5
                  const float* __restrict__ W_b, const float* __restrict__ Q_b,
                  const float* __restrict__ aim, const float* __restrict__ detect,
                  float* __restrict__ out_aim, float* __restrict__ out_det)
{
    const int z = blockIdx.z;
    const unsigned short* A = z ? ND : NA;
    const unsigned short* Wm = Wb + (size_t)(z ? 5 : 4) * 65536;
    const float* Bv = z ? Q_b : W_b;
    const float* R  = z ? detect : aim;
    float* O = z ? out_det : out_aim;
    const int m0 = blockIdx.y * 64, n0 = blockIdx.x * 128;

    __shared__ unsigned short As[64][40], Bs[128][40];
    const int tid = threadIdx.x, lane = tid & 63, w = tid >> 6;
    const int wr = w >> 1, wc = w & 1, q = lane >> 4, ln = lane & 15;

    f32x4 acc[2][4] = {};

    for (int k0 = 0; k0 < 256; k0 += 32) {
        {                                        // A bf16: 64x32 = 256 u16x8
            int row = tid >> 2, c8 = tid & 3;
            *(u16x8*)&As[row][c8 * 8] = *(const u16x8*)(A + (size_t)(m0 + row) * 256 + k0 + c8 * 8);
        }
        #pragma unroll
        for (int i = 0; i < 2; ++i) {            // W bf16: 128x32 = 512 u16x8
            int c = tid + i * 256, row = c >> 2, c8 = c & 3;
            *(u16x8*)&Bs[row][c8 * 8] = *(const u16x8*)(Wm + (size_t)(n0 + row) * 256 + k0 + c8 * 8);
        }
        __syncthreads();
        bf16x8 af[2], bb[4];
        #pragma unroll
        for (int i = 0; i < 2; ++i) af[i] = ldfrag(&As[wr * 32 + i * 16 + ln][q * 8]);
        #pragma unroll
        for (int j = 0; j < 4; ++j) bb[j] = ldfrag(&Bs[wc * 64 + j * 16 + ln][q * 8]);
        #pragma unroll
        for (int i = 0; i < 2; ++i)
            #pragma unroll
            for (int j = 0; j < 4; ++j)
                acc[i][j] = __builtin_amdgcn_mfma_f32_16x16x32_bf16(af[i], bb[j], acc[i][j], 0, 0, 0);
        __syncthreads();
    }

    #pragma unroll
    for (int i = 0; i < 2; ++i)
        #pragma unroll
        for (int j = 0; j < 4; ++j) {
            int n = n0 + wc * 64 + j * 16 + ln;
            float bias = Bv[n];
            #pragma unroll
            for (int r = 0; r < 4; ++r) {
                int m = m0 + wr * 32 + i * 16 + q * 4 + r;
                O[(size_t)m * 256 + n] = acc[i][j][r] + bias + R[(size_t)m * 256 + n];
            }
        }
}

extern "C" void kernel_launch(void* const* d_in, const int* in_sizes, int n_in,
                              void* d_out, int out_size, void* d_ws, size_t ws_size,
                              hipStream_t stream)
{
    const float* detect = (const float*)d_in[0];
    const float* aim    = (const float*)d_in[1];
    const float* g_w  = (const float*)d_in[2];  const float* g_b  = (const float*)d_in[3];
    const float* g2_w = (const float*)d_in[4];  const float* g2_b = (const float*)d_in[5];
    const float* th_w = (const float*)d_in[6];  const float* th_b = (const float*)d_in[7];
    const float* ph_w = (const float*)d_in[8];  const float* ph_b = (const float*)d_in[9];
    const float* W_w  = (const float*)d_in[10]; const float* W_b  = (const float*)d_in[11];
    const float* Q_w  = (const float*)d_in[12]; const float* Q_b  = (const float*)d_in[13];

    const size_t TOT = 8192L * 256;   // 2,097,152 elems per tensor

    unsigned short* ws16 = (unsigned short*)d_ws;
    unsigned short* Wbf = ws16;                 // [6][65536]: g,g2,th,ph,W,Q
    unsigned short* Abf = Wbf + 6 * 65536;      // aim bf16
    unsigned short* Dbf = Abf + TOT;            // detect bf16
    unsigned short* T   = Dbf + TOT;
    unsigned short* P   = T  + TOT;
    unsigned short* Gd  = P  + TOT;
    unsigned short* Ga  = Gd + TOT;
    unsigned short* NA  = Ga + TOT;
    unsigned short* ND  = NA + TOT;
    float* S     = (float*)(ND + TOT);          // [2][4][128][128]
    float* Spart = S + 2 * 4 * 16384;           // [2][4][32][128][128]

    float* out_det = (float*)d_out;
    float* out_aim = out_det + TOT;

    prep_kernel<<<dim3(256, 8), 256, 0, stream>>>(
        g_w, g2_w, th_w, ph_w, W_w, Q_w, aim, detect, Wbf);
    lin4_kernel<<<dim3(2, 128, 2), 256, 0, stream>>>(
        Abf, Dbf, Wbf, g_b, g2_b, th_b, ph_b, T, Ga, P, Gd);
    s_part_kernel<<<dim3(256), 256, 0, stream>>>(Gd, P, Ga, T, Spart);
    sred_kernel<<<dim3(512), 256, 0, stream>>>(Spart, S);
    nand_kernel<<<dim3(64, 1, 8), 256, 0, stream>>>(S, T, P, NA, ND);
    final_kernel<<<dim3(2, 128, 2), 256, 0, stream>>>(
        NA, ND, Wbf, W_b, Q_b, aim, detect, out_aim, out_det);
}